// Round 3
// baseline (540.958 us; speedup 1.0000x reference)
//
#include <hip/hip_runtime.h>

typedef unsigned short u16;
typedef unsigned int   u32;

typedef __attribute__((ext_vector_type(8))) __bf16 bf16x8;
typedef __attribute__((ext_vector_type(8))) unsigned short u16x8;
typedef __attribute__((ext_vector_type(4))) float  f32x4;

#define C      256
#define OUTC   128
#define LN_EPS 1e-5f

__device__ __forceinline__ float bf2f(u16 u) {
    u32 i = ((u32)u) << 16; float f; __builtin_memcpy(&f, &i, 4); return f;
}
__device__ __forceinline__ u16 f2bf(float f) {
    u32 i; __builtin_memcpy(&i, &f, 4);
    u32 r = (i + 0x7FFFu + ((i >> 16) & 1u)) >> 16;
    return (u16)r;
}
__device__ __forceinline__ void load_lds16(const void* g, void* l) {
    __builtin_amdgcn_global_load_lds((const __attribute__((address_space(1))) u32*)g,
                                     (__attribute__((address_space(3))) u32*)l, 16, 0, 0);
}
// legacy swizzle for final_gemm (unchanged this round)
__device__ __forceinline__ int swz(int row) { return (row + (row >> 2)) & 3; }

// ---- combined prep: weights (blocks < PREP_BLK) + x->bf16 cast (rest) ------------
#define PREP_BLK 1408   // (256*512 + 256*768 + 128*256) / 256
__global__ void prep_combo(const float* wl0, const float* w00, const float* w10,
                           const float* bl0, const float* b00, const float* b10,
                           const float* gate0,
                           const float* wl1, const float* w01, const float* w11,
                           const float* bl1, const float* b01, const float* b11,
                           const float* gate1,
                           const float* Wout, const float* x,
                           u16* __restrict__ WcatA, u16* __restrict__ WcatB,
                           u16* __restrict__ Woutb, float* __restrict__ bcat,
                           u16* __restrict__ xb, size_t n8)
{
    if (blockIdx.x >= PREP_BLK) {
        size_t i = ((size_t)(blockIdx.x - PREP_BLK) * 256 + threadIdx.x);
        if (i >= n8) return;
        const float* p = x + i * 8;
        float4 v0 = *(const float4*)p;
        float4 v1 = *(const float4*)(p + 4);
        u16x8 o;
        o[0] = f2bf(v0.x); o[1] = f2bf(v0.y); o[2] = f2bf(v0.z); o[3] = f2bf(v0.w);
        o[4] = f2bf(v1.x); o[5] = f2bf(v1.y); o[6] = f2bf(v1.z); o[7] = f2bf(v1.w);
        *(u16x8*)(xb + i * 8) = o;
        return;
    }
    int idx = blockIdx.x * 256 + threadIdx.x;
    float gA = 1.f / (1.f + expf(-gate1[0]));   // layer processed FIRST uses params *1
    float gB = 1.f / (1.f + expf(-gate0[0]));
    if (idx < 256 * 512) {
        int n = idx >> 9, k = idx & 511;
        float v;
        if (k < 256) v = wl1[n * 256 + k];
        else         v = (1.f - gA) * w01[n * 256 + (k - 256)] + gA * w11[n * 256 + (k - 256)];
        WcatA[idx] = f2bf(v);
    } else if (idx < 256 * 512 + 256 * 768) {
        int j = idx - 256 * 512;
        int n = j / 768, k = j - n * 768;
        float v;
        if (k < 256)      v = wl0[n * 256 + k];
        else if (k < 512) v = (1.f - gB) * w00[n * 256 + (k - 256)];
        else              v = gB * w10[n * 256 + (k - 512)];
        WcatB[j] = f2bf(v);
    } else {
        int j = idx - (256 * 512 + 256 * 768);
        if (j < OUTC * C) Woutb[j] = f2bf(Wout[j]);
    }
    if (idx < 512) {
        int nn = idx & 255;
        if (idx < 256) bcat[idx] = bl1[nn] + (1.f - gA) * b01[nn] + gA * b11[nn];
        else           bcat[idx] = bl0[nn] + (1.f - gB) * b00[nn] + gB * b10[nn];
    }
}

// ================= CSR build (both graphs per launch) =============================
__global__ void count_edges2(const int* __restrict__ ei1, const int* __restrict__ ei0,
                             int* __restrict__ cnt1, int* __restrict__ deg1,
                             int* __restrict__ cnt0, int* __restrict__ deg0,
                             int E, int Nn, int ebg)
{
    int b = blockIdx.x;
    const int* ei; int *cnt, *deg;
    if (b < ebg) { ei = ei1; cnt = cnt1; deg = deg1; }
    else         { b -= ebg; ei = ei0; cnt = cnt0; deg = deg0; }
    int idx = b * 256 + threadIdx.x;
    if (idx >= E) return;
    int s = ei[idx], d = ei[E + idx];
    if ((unsigned)s >= (unsigned)Nn || (unsigned)d >= (unsigned)Nn) return;
    atomicAdd(cnt + s, 1);
    atomicAdd(deg + d, 1);
}

__global__ void block_sums2(const int* __restrict__ cnt1, const int* __restrict__ cnt0,
                            int* __restrict__ parts1, int* __restrict__ parts0,
                            int n, int nblk)
{
    int b = blockIdx.x;
    const int* counts; int* partials;
    if (b < nblk) { counts = cnt1; partials = parts1; }
    else          { b -= nblk; counts = cnt0; partials = parts0; }
    int i = b * 256 + threadIdx.x;
    int v = (i < n) ? counts[i] : 0;
    #pragma unroll
    for (int off = 32; off; off >>= 1) v += __shfl_down(v, off, 64);
    __shared__ int ws[4];
    if ((threadIdx.x & 63) == 0) ws[threadIdx.x >> 6] = v;
    __syncthreads();
    if (threadIdx.x == 0) partials[b] = ws[0] + ws[1] + ws[2] + ws[3];
}

__global__ void scan_partials2(int* __restrict__ parts1, int* __restrict__ parts0, int nblk)
{
    int* partials = blockIdx.x ? parts0 : parts1;
    __shared__ int buf[1024];
    int tid = threadIdx.x;
    int v = (tid < nblk) ? partials[tid] : 0;
    buf[tid] = v; __syncthreads();
    for (int off = 1; off < 1024; off <<= 1) {
        int t = (tid >= off) ? buf[tid - off] : 0;
        __syncthreads();
        buf[tid] += t;
        __syncthreads();
    }
    if (tid < nblk) partials[tid] = buf[tid] - v;
}

__global__ void make_offsets2(int* __restrict__ cnt1, int* __restrict__ cnt0,
                              const int* __restrict__ parts1, const int* __restrict__ parts0,
                              int* __restrict__ off1a, int* __restrict__ off0a,
                              int n, int nblk)
{
    int b = blockIdx.x;
    int* counts_cursor; const int* partials; int* offsets;
    if (b < nblk) { counts_cursor = cnt1; partials = parts1; offsets = off1a; }
    else          { b -= nblk; counts_cursor = cnt0; partials = parts0; offsets = off0a; }
    __shared__ int buf[256];
    int i = b * 256 + threadIdx.x;
    int cnt = (i < n) ? counts_cursor[i] : 0;
    buf[threadIdx.x] = cnt; __syncthreads();
    for (int off = 1; off < 256; off <<= 1) {
        int t = (threadIdx.x >= off) ? buf[threadIdx.x - off] : 0;
        __syncthreads();
        buf[threadIdx.x] += t;
        __syncthreads();
    }
    int off = partials[b] + buf[threadIdx.x] - cnt;
    if (i < n) {
        offsets[i] = off;
        counts_cursor[i] = off;
        if (i == n - 1) offsets[n] = off + cnt;
    }
}

__global__ void fill_edges2(const int* __restrict__ ei1, const int* __restrict__ ei0,
                            int* __restrict__ cur1, int* __restrict__ cur0,
                            int* __restrict__ ed1, int* __restrict__ ed0,
                            int E, int Nn, int ebg)
{
    int b = blockIdx.x;
    const int* ei; int *cursor, *edgedst;
    if (b < ebg) { ei = ei1; cursor = cur1; edgedst = ed1; }
    else         { b -= ebg; ei = ei0; cursor = cur0; edgedst = ed0; }
    int idx = b * 256 + threadIdx.x;
    if (idx >= E) return;
    int s = ei[idx], d = ei[E + idx];
    if ((unsigned)s >= (unsigned)Nn || (unsigned)d >= (unsigned)Nn) return;
    int p = atomicAdd(cursor + s, 1);
    edgedst[p] = d;
}

// ---- gather: one wave per node; lanes 0-31 / 32-63 cover 2 edges, 16B per lane ---
__global__ __launch_bounds__(256) void gather_kernel(
    const int* __restrict__ offsets, const int* __restrict__ edgedst,
    const int* __restrict__ degcnt, const u16* __restrict__ h,
    u16* __restrict__ aggb, int Nn)
{
    int node = blockIdx.x * 4 + (threadIdx.x >> 6);
    if (node >= Nn) return;
    int lane = threadIdx.x & 63;
    int half = lane >> 5, l5 = lane & 31;
    int beg = offsets[node], end = offsets[node + 1];
    float a0[8] = {}, a1[8] = {};
    int p = beg;
    for (; p + 3 < end; p += 4) {              // 4 edges in flight
        int d0 = edgedst[p + half];
        int d1 = edgedst[p + 2 + half];
        u16x8 v0 = *(const u16x8*)(h + (size_t)d0 * C + l5 * 8);
        u16x8 v1 = *(const u16x8*)(h + (size_t)d1 * C + l5 * 8);
        #pragma unroll
        for (int j = 0; j < 8; ++j) { a0[j] += bf2f(v0[j]); a1[j] += bf2f(v1[j]); }
    }
    if (p + 1 < end) {                         // remaining pair
        int d0 = edgedst[p + half];
        u16x8 v0 = *(const u16x8*)(h + (size_t)d0 * C + l5 * 8);
        #pragma unroll
        for (int j = 0; j < 8; ++j) a0[j] += bf2f(v0[j]);
        p += 2;
    }
    if (p < end && half == 0) {                // odd tail: lanes 0-31 only
        int d0 = edgedst[p];
        u16x8 v0 = *(const u16x8*)(h + (size_t)d0 * C + l5 * 8);
        #pragma unroll
        for (int j = 0; j < 8; ++j) a1[j] += bf2f(v0[j]);
    }
    float inv = 1.0f / fmaxf((float)degcnt[node], 1.0f);
    u16x8 o;
    #pragma unroll
    for (int j = 0; j < 8; ++j) {
        float s = a0[j] + a1[j];
        s += __shfl_xor(s, 32);                // combine edge-halves
        o[j] = f2bf(s * inv);
    }
    if (half == 0)
        *(u16x8*)(aggb + (size_t)node * C + l5 * 8) = o;
}

// =================================================================================
// layer_gemm8: m201-style 256x256 8-phase GEMM with fused bias+ReLU+LN epilogue.
// BM=256, BN=256, BK=64 (2 k-halves of 32). 512 thr = 8 waves (2Mx4N), each wave
// owns 128x64 (acc[8][4]). LDS (dynamic, 136KB): A[2buf][2kh][256x32], B same,
// lnpart[256][4][2]. Per K-tile: 4 phases {kh,mh}, 16 MFMA each, 2 barriers/phase,
// setprio around MFMA, stage 2 loads/phase into buf^1, vmcnt(6) at p0/p2 only.
// LDS element (r,c16B): phys slot = (((r&1)<<2)|c) ^ ((r>>1)&7)  -> 2-way banks.
// global_load_lds dest is linear; the swizzle is applied on the GLOBAL source.
// =================================================================================
template <int NSEG>
__global__ __launch_bounds__(512, 2) void layer_gemm8(
    const u16* __restrict__ s0, const u16* __restrict__ s1, const u16* __restrict__ s2,
    const u16* __restrict__ W,          // [256][NSEG*256] bf16
    const float* __restrict__ bcat,
    const float* __restrict__ lns, const float* __restrict__ lnb,
    u16* __restrict__ Hout, int Nnodes)
{
    constexpr int WK = NSEG * 256;
    constexpr int T  = NSEG * 4;               // K-tiles of 64

    extern __shared__ char smem[];
    u16*   A_e    = (u16*)smem;                // 2 x 16384 elements (64KB)
    u16*   B_e    = (u16*)(smem + 65536);      // 2 x 16384 elements (64KB)
    float* lnpart = (float*)(smem + 131072);   // [256][4][2] (8KB)

    const int tid  = threadIdx.x;
    const int wave = tid >> 6, lane = tid & 63;
    const int wave_m = wave & 1, wave_n = wave >> 1;   // 2 x 4
    const int q = lane >> 4, l15 = lane & 15;
    const int m0 = blockIdx.x * 256;

    // ---- staging address precompute (2 global_load_lds per 16KB half-tile) ----
    size_t a_goff[2], b_goff[2];
    int ldso[2];
    #pragma unroll
    for (int i = 0; i < 2; ++i) {
        int o = i * 8192 + wave * 1024 + lane * 16;    // linear byte off in half
        int g = o >> 7, slot = (o >> 4) & 7;
        int bc = slot ^ (g & 7);
        int r = 2 * g + (bc >> 2), c = bc & 3;         // logical row/chunk at o
        int node = m0 + r; if (node >= Nnodes) node = Nnodes - 1;
        a_goff[i] = (size_t)node * C + c * 8;
        b_goff[i] = (size_t)r * WK + c * 8;
        ldso[i]   = i * 8192 + wave * 1024;            // wave-uniform LDS base
    }

    // ---- fragment read offsets (elements, within one 8192-elem half) ----
    int aoffE[8], boffE[4];
    #pragma unroll
    for (int j = 0; j < 8; ++j) {
        int r = wave_m * 128 + j * 16 + l15;
        aoffE[j] = (r >> 1) * 64 + (((((r & 1) << 2) | q) ^ ((r >> 1) & 7)) << 3);
    }
    #pragma unroll
    for (int f = 0; f < 4; ++f) {
        int r = wave_n * 64 + f * 16 + l15;
        boffE[f] = (r >> 1) * 64 + (((((r & 1) << 2) | q) ^ ((r >> 1) & 7)) << 3);
    }

    f32x4 acc[8][4] = {};

    auto stA = [&](int buf, int kh, int t) {
        const u16* sp = (t < 4) ? s0 : ((NSEG == 2 || t < 8) ? s1 : s2);
        const u16* base = sp + ((t & 3) << 6) + (kh << 5);
        #pragma unroll
        for (int i = 0; i < 2; ++i)
            load_lds16(base + a_goff[i], (char*)A_e + buf * 32768 + kh * 16384 + ldso[i]);
    };
    auto stB = [&](int buf, int kh, int t) {
        const u16* base = W + (t << 6) + (kh << 5);
        #pragma unroll
        for (int i = 0; i < 2; ++i)
            load_lds16(base + b_goff[i], (char*)B_e + buf * 32768 + kh * 16384 + ldso[i]);
    };

#define LDA(DST, BASE, MH) \
    _Pragma("unroll") for (int j = 0; j < 4; ++j) \
        DST[j] = *(const bf16x8*)((BASE) + aoffE[(MH) * 4 + j]);
#define LDB(DST, BASE) \
    _Pragma("unroll") for (int f = 0; f < 4; ++f) \
        DST[f] = *(const bf16x8*)((BASE) + boffE[f]);
#define MFMA16(MH, AF, BF) \
    _Pragma("unroll") for (int j = 0; j < 4; ++j) \
        _Pragma("unroll") for (int f = 0; f < 4; ++f) \
            acc[(MH) * 4 + j][f] = __builtin_amdgcn_mfma_f32_16x16x32_bf16( \
                AF[j], BF[f], acc[(MH) * 4 + j][f], 0, 0, 0);
#define SBAR()  asm volatile("s_barrier" ::: "memory")

    // prologue: all 4 half-tiles of K-tile 0 (8 loads in flight)
    stA(0, 0, 0); stB(0, 0, 0); stA(0, 1, 0); stB(0, 1, 0);

    int cur = 0;
    for (int t = 0; t < T - 1; ++t, cur ^= 1) {
        const u16* Ac = A_e + cur * 16384;
        const u16* Bc = B_e + cur * 16384;
        const int nxt = cur ^ 1;
        bf16x8 af[4], bfr[4];
        // ---- p0: kh=0, mh=0 ----
        stA(nxt, 0, t + 1);
        asm volatile("s_waitcnt vmcnt(6)" ::: "memory");   // oldest 4 = kh0 A+B of t
        SBAR();
        __builtin_amdgcn_sched_barrier(0);
        LDB(bfr, Bc); LDA(af, Ac, 0);
        __builtin_amdgcn_s_setprio(1);
        MFMA16(0, af, bfr);
        __builtin_amdgcn_s_setprio(0);
        SBAR();
        // ---- p1: kh=0, mh=1 ----
        LDA(af, Ac, 1);
        stB(nxt, 0, t + 1);
        SBAR();
        __builtin_amdgcn_s_setprio(1);
        MFMA16(1, af, bfr);
        __builtin_amdgcn_s_setprio(0);
        SBAR();
        // ---- p2: kh=1, mh=0 ----
        stA(nxt, 1, t + 1);
        asm volatile("s_waitcnt vmcnt(6)" ::: "memory");   // oldest 4 = kh1 A+B of t
        SBAR();
        __builtin_amdgcn_sched_barrier(0);
        LDB(bfr, Bc + 8192); LDA(af, Ac + 8192, 0);
        __builtin_amdgcn_s_setprio(1);
        MFMA16(0, af, bfr);
        __builtin_amdgcn_s_setprio(0);
        SBAR();
        // ---- p3: kh=1, mh=1 ----
        LDA(af, Ac + 8192, 1);
        stB(nxt, 1, t + 1);
        SBAR();
        __builtin_amdgcn_s_setprio(1);
        MFMA16(1, af, bfr);
        __builtin_amdgcn_s_setprio(0);
        SBAR();
    }
    {   // ---- tail K-tile (no staging; drain) ----
        const u16* Ac = A_e + cur * 16384;
        const u16* Bc = B_e + cur * 16384;
        bf16x8 af[4], bfr[4];
        asm volatile("s_waitcnt vmcnt(4)" ::: "memory");
        SBAR();
        __builtin_amdgcn_sched_barrier(0);
        LDB(bfr, Bc); LDA(af, Ac, 0);
        __builtin_amdgcn_s_setprio(1);
        MFMA16(0, af, bfr);
        __builtin_amdgcn_s_setprio(0);
        SBAR();
        LDA(af, Ac, 1);
        SBAR();
        __builtin_amdgcn_s_setprio(1);
        MFMA16(1, af, bfr);
        __builtin_amdgcn_s_setprio(0);
        SBAR();
        asm volatile("s_waitcnt vmcnt(0)" ::: "memory");
        SBAR();
        __builtin_amdgcn_sched_barrier(0);
        LDB(bfr, Bc + 8192); LDA(af, Ac + 8192, 0);
        __builtin_amdgcn_s_setprio(1);
        MFMA16(0, af, bfr);
        __builtin_amdgcn_s_setprio(0);
        SBAR();
        LDA(af, Ac + 8192, 1);
        SBAR();
        __builtin_amdgcn_s_setprio(1);
        MFMA16(1, af, bfr);
        __builtin_amdgcn_s_setprio(0);
        SBAR();
    }

    // ---- fused epilogue: bias + relu + LN -> bf16 ----
    float bias[4], lsc[4], lbi[4];
    #pragma unroll
    for (int f = 0; f < 4; ++f) {
        int n = wave_n * 64 + f * 16 + l15;
        bias[f] = bcat[n]; lsc[f] = lns[n]; lbi[f] = lnb[n];
    }
    #pragma unroll
    for (int t8 = 0; t8 < 8; ++t8)
        #pragma unroll
        for (int r = 0; r < 4; ++r) {
            float p = 0.f, pp = 0.f;
            #pragma unroll
            for (int f = 0; f < 4; ++f) {
                float v = acc[t8][f][r] + bias[f];
                v = fmaxf(v, 0.f);
                acc[t8][f][r] = v;
                p += v; pp += v * v;
            }
            #pragma unroll
            for (int off = 1; off < 16; off <<= 1) {
                p  += __shfl_xor(p,  off, 16);
                pp += __shfl_xor(pp, off, 16);
            }
            if (l15 == 0) {
                int row = wave_m * 128 + t8 * 16 + q * 4 + r;
                lnpart[row * 8 + wave_n * 2 + 0] = p;
                lnpart[row * 8 + wave_n * 2 + 1] = pp;
            }
        }
    __syncthreads();
    #pragma unroll
    for (int t8 = 0; t8 < 8; ++t8)
        #pragma unroll
        for (int r = 0; r < 4; ++r) {
            int row = wave_m * 128 + t8 * 16 + q * 4 + r;
            int node = m0 + row;
            if (node < Nnodes) {
                float S1 = lnpart[row * 8 + 0] + lnpart[row * 8 + 2]
                         + lnpart[row * 8 + 4] + lnpart[row * 8 + 6];
                float S2 = lnpart[row * 8 + 1] + lnpart[row * 8 + 3]
                         + lnpart[row * 8 + 5] + lnpart[row * 8 + 7];
                float mean = S1 * (1.f / 256.f);
                float var  = fmaxf(S2 * (1.f / 256.f) - mean * mean, 0.f);
                float rstd = rsqrtf(var + LN_EPS);
                u16* op = Hout + (size_t)node * C;
                #pragma unroll
                for (int f = 0; f < 4; ++f) {
                    int n = wave_n * 64 + f * 16 + l15;
                    op[n] = f2bf((acc[t8][f][r] - mean) * rstd * lsc[f] + lbi[f]);
                }
            }
        }
#undef LDA
#undef LDB
#undef MFMA16
#undef SBAR
}

// ---- final GEMM (128x128 tile): h2(bf16, in d_out) @ Woutb^T + bout -> fp32 in place
// counted-vmcnt double-buffered pipeline (unchanged this round).
__global__ __launch_bounds__(512, 4) void final_gemm(
    const u16* __restrict__ A, const u16* __restrict__ W,
    const float* __restrict__ bout, float* __restrict__ out, int Nnodes)
{
    __shared__ u16 Alds[2][128 * 32];   // 16 KB
    __shared__ u16 Blds[2][128 * 32];   // 16 KB

    const int tid = threadIdx.x;
    const int wave = tid >> 6, lane = tid & 63;
    const int wave_m = wave & 1, wave_n = wave >> 1;   // 2 x 4
    const int q = lane >> 4, l15 = lane & 15;
    const int m0 = blockIdx.x * 128;

    const int srow = (wave << 4) + (lane >> 2);
    int anode = m0 + srow; if (anode >= Nnodes) anode = Nnodes - 1;
    const int asc = (lane & 3) ^ swz(srow);
    const size_t a_goff = (size_t)anode * C + asc * 8;
    const int a_lo = wave << 9;

    const int bsc = (lane & 3) ^ swz(srow);
    const u16* bgp = W + srow * C + bsc * 8;
    const int b_lo = wave << 9;

    int aoff[4], boff[2];
    #pragma unroll
    for (int t = 0; t < 4; ++t) {
        int ar = wave_m * 64 + t * 16 + l15;
        aoff[t] = ar * 32 + ((q ^ swz(ar)) << 3);
    }
    #pragma unroll
    for (int f = 0; f < 2; ++f) {
        int br = wave_n * 32 + f * 16 + l15;
        boff[f] = br * 32 + ((q ^ swz(br)) << 3);
    }

    f32x4 acc[4][2] = {};

    auto stage = [&](int b, int kt) {
        int k0 = kt << 5;
        load_lds16(A + a_goff + k0, &Alds[b][a_lo]);
        load_lds16(bgp + k0, &Blds[b][b_lo]);
    };
    auto compute = [&](const u16* __restrict__ Ab, const u16* __restrict__ Bb) {
        bf16x8 af[4], bfr[2];
        #pragma unroll
        for (int t = 0; t < 4; ++t) af[t]  = *(const bf16x8*)(Ab + aoff[t]);
        #pragma unroll
        for (int f = 0; f < 2; ++f) bfr[f] = *(const bf16x8*)(Bb + boff[f]);
        #pragma unroll
        for (int t = 0; t < 4; ++t)
            #pragma unroll
            for (int f = 0; f < 2; ++f)
                acc[t][f] = __builtin_amdgcn_mfma_f32_16x16x32_bf16(af[t], bfr[f], acc[t][f], 0, 0, 0);
    };

    stage(0, 0);      // 2 in flight
    stage(1, 1);      // 4 in flight
    for (int kt = 0; kt < 6; kt += 2) {
        asm volatile("s_waitcnt vmcnt(2)" ::: "memory");
        __builtin_amdgcn_s_barrier();
        __builtin_amdgcn_sched_barrier(0);
        compute(&Alds[0][0], &Blds[0][0]);
        __builtin_amdgcn_sched_barrier(0);
        __builtin_amdgcn_s_barrier();
        stage(0, kt + 2);
        asm volatile("s_waitcnt vmcnt(2)" ::: "memory");
        __builtin_amdgcn_s_barrier();
        __builtin_amdgcn_sched_barrier(0);
        compute(&Alds[1][0], &Blds[1][0]);
        __builtin_amdgcn_sched_barrier(0);
        __builtin_amdgcn_s_barrier();
        stage(1, kt + 3);
    }
    asm volatile("s_waitcnt vmcnt(2)" ::: "memory");
    __builtin_amdgcn_s_barrier();
    __builtin_amdgcn_sched_barrier(0);
    compute(&Alds[0][0], &Blds[0][0]);
    asm volatile("s_waitcnt vmcnt(0)" ::: "memory");
    __builtin_amdgcn_s_barrier();
    __builtin_amdgcn_sched_barrier(0);
    compute(&Alds[1][0], &Blds[1][0]);

    float bias[2];
    #pragma unroll
    for (int f = 0; f < 2; ++f) bias[f] = bout[wave_n * 32 + f * 16 + l15];
    #pragma unroll
    for (int t = 0; t < 4; ++t)
        #pragma unroll
        for (int r = 0; r < 4; ++r) {
            int row = wave_m * 64 + t * 16 + q * 4 + r;
            int node = m0 + row;
            if (node < Nnodes) {
                float* op = out + (size_t)node * OUTC;
                #pragma unroll
                for (int f = 0; f < 2; ++f) {
                    int n = wave_n * 32 + f * 16 + l15;
                    op[n] = acc[t][f][r] + bias[f];
                }
            }
        }
}

extern "C" void kernel_launch(void* const* d_in, const int* in_sizes, int n_in,
                              void* d_out, int out_size, void* d_ws, size_t ws_size,
                              hipStream_t stream)
{
    const float* x    = (const float*)d_in[0];
    const int*   ei0  = (const int*)d_in[1];
    const int*   ei1  = (const int*)d_in[2];
    const float* wl0  = (const float*)d_in[3];
    const float* bl0  = (const float*)d_in[4];
    const float* w00  = (const float*)d_in[5];
    const float* b00  = (const float*)d_in[6];
    const float* w10  = (const float*)d_in[7];
    const float* b10  = (const float*)d_in[8];
    const float* gate0= (const float*)d_in[9];
    const float* lns0 = (const float*)d_in[10];
    const float* lnb0 = (const float*)d_in[11];
    const float* wl1  = (const float*)d_in[12];
    const float* bl1  = (const float*)d_in[13];
    const float* w01  = (const float*)d_in[14];
    const float* b01  = (const float*)d_in[15];
    const float* w11  = (const float*)d_in[16];
    const float* b11  = (const float*)d_in[17];
    const float* gate1= (const float*)d_in[18];
    const float* lns1 = (const float*)d_in[19];
    const float* lnb1 = (const float*)d_in[20];
    const float* Wout = (const float*)d_in[21];
    const float* bout = (const float*)d_in[22];

    const int N = in_sizes[0] / C;     // 100000
    const int E = in_sizes[1] / 2;     // 400000

    // workspace (~161 MiB)
    char* w = (char*)d_ws;
    u16*   WcatA = (u16*)w;   w += (size_t)256 * 512 * 2;
    u16*   WcatB = (u16*)w;   w += (size_t)256 * 768 * 2;
    u16*   Woutb = (u16*)w;   w += (size_t)OUTC * C * 2;
    float* bcat  = (float*)w; w += 4096;
    int*   cnt1  = (int*)w;   w += (size_t)N * 4;       // 4 contiguous, one memset
    int*   deg1  = (int*)w;   w += (size_t)N * 4;
    int*   cnt0  = (int*)w;   w += (size_t)N * 4;
    int*   deg0  = (int*)w;   w += (size_t)N * 4;
    int*   off1  = (int*)w;   w += (((size_t)(N + 1) * 4) + 255) & ~255ull;
    int*   off0  = (int*)w;   w += (((size_t)(N + 1) * 4) + 255) & ~255ull;
    int*   parts1= (int*)w;   w += 4096;
    int*   parts0= (int*)w;   w += 4096;
    int*   ed1   = (int*)w;   w += (size_t)E * 4;
    int*   ed0   = (int*)w;   w += (size_t)E * 4;
    u16*   xb    = (u16*)w;   w += (size_t)N * C * 2;   // 51.2 MB bf16 copy of x
    u16*   aggb  = (u16*)w;   w += (size_t)N * C * 2;   // 51.2 MB (reused both layers)
    u16*   h1    = (u16*)w;   w += (size_t)N * C * 2;   // 51.2 MB

    const int eb_grid = (E + 255) / 256;
    const int nblk    = (N + 255) / 256;                // 391 <= 1024
    const int gt_grid = (N + 3) / 4;
    const int gm_grid = (N + 127) / 128;
    const int gm8     = (N + 255) / 256;                // 391 blocks, 256-row tiles
    const size_t n8   = (size_t)N * C / 8;
    const int xc_blk  = (int)((n8 + 255) / 256);
    const size_t lds8 = 139264;                         // 128KB tiles + 8KB lnpart
    u16* h2 = (u16*)d_out;   // layer-B bf16 output in d_out; final_gemm overwrites in place

    hipMemsetAsync(cnt1, 0, (size_t)4 * N * 4, stream);
    prep_combo<<<PREP_BLK + xc_blk, 256, 0, stream>>>(
        wl0, w00, w10, bl0, b00, b10, gate0,
        wl1, w01, w11, bl1, b01, b11, gate1,
        Wout, x, WcatA, WcatB, Woutb, bcat, xb, n8);

    // ---- CSR builds, both graphs per launch ----
    count_edges2 <<<2 * eb_grid, 256, 0, stream>>>(ei1, ei0, cnt1, deg1, cnt0, deg0, E, N, eb_grid);
    block_sums2  <<<2 * nblk, 256, 0, stream>>>(cnt1, cnt0, parts1, parts0, N, nblk);
    scan_partials2<<<2, 1024, 0, stream>>>(parts1, parts0, nblk);
    make_offsets2<<<2 * nblk, 256, 0, stream>>>(cnt1, cnt0, parts1, parts0, off1, off0, N, nblk);
    fill_edges2  <<<2 * eb_grid, 256, 0, stream>>>(ei1, ei0, cnt1, cnt0, ed1, ed0, E, N, eb_grid);

    // ---- layer A: graph ei1, params *1, h = x0 = xb; K = 512 (w0,w1 folded) ----
    gather_kernel<<<gt_grid, 256, 0, stream>>>(off1, ed1, deg1, xb, aggb, N);
    layer_gemm8<2><<<gm8, 512, lds8, stream>>>(aggb, xb, nullptr, WcatA, bcat,
                                               lns1, lnb1, h1, N);

    // ---- layer B: graph ei0, params *0, h = h1, x0 = xb; K = 768 ----
    gather_kernel<<<gt_grid, 256, 0, stream>>>(off0, ed0, deg0, h1, aggb, N);
    layer_gemm8<3><<<gm8, 512, lds8, stream>>>(aggb, h1, xb, WcatB, bcat + C,
                                               lns0, lnb0, h2, N);

    // ---- output projection (128x128 tile, in place over d_out) ----
    final_gemm<<<gm_grid, 512, 0, stream>>>(h2, Woutb, bout, (float*)d_out, N);
}

// Round 5
// 528.614 us; speedup vs baseline: 1.0234x; 1.0234x over previous
//
#include <hip/hip_runtime.h>

typedef unsigned short u16;
typedef unsigned int   u32;

typedef __attribute__((ext_vector_type(8))) __bf16 bf16x8;
typedef __attribute__((ext_vector_type(8))) unsigned short u16x8;
typedef __attribute__((ext_vector_type(4))) float  f32x4;

#define C      256
#define OUTC   128
#define LN_EPS 1e-5f

__device__ __forceinline__ float bf2f(u16 u) {
    u32 i = ((u32)u) << 16; float f; __builtin_memcpy(&f, &i, 4); return f;
}
__device__ __forceinline__ u16 f2bf(float f) {
    u32 i; __builtin_memcpy(&i, &f, 4);
    u32 r = (i + 0x7FFFu + ((i >> 16) & 1u)) >> 16;
    return (u16)r;
}
__device__ __forceinline__ void load_lds16(const void* g, void* l) {
    __builtin_amdgcn_global_load_lds((const __attribute__((address_space(1))) u32*)g,
                                     (__attribute__((address_space(3))) u32*)l, 16, 0, 0);
}

// ---- combined prep: weights (blocks < PREP_BLK) + x->bf16 cast (rest) ------------
#define PREP_BLK 1408   // (256*512 + 256*768 + 128*256) / 256
__global__ void prep_combo(const float* wl0, const float* w00, const float* w10,
                           const float* bl0, const float* b00, const float* b10,
                           const float* gate0,
                           const float* wl1, const float* w01, const float* w11,
                           const float* bl1, const float* b01, const float* b11,
                           const float* gate1,
                           const float* Wout, const float* x,
                           u16* __restrict__ WcatA, u16* __restrict__ WcatB,
                           u16* __restrict__ Woutb, float* __restrict__ bcat,
                           u16* __restrict__ xb, size_t n8)
{
    if (blockIdx.x >= PREP_BLK) {
        size_t i = ((size_t)(blockIdx.x - PREP_BLK) * 256 + threadIdx.x);
        if (i >= n8) return;
        const float* p = x + i * 8;
        float4 v0 = *(const float4*)p;
        float4 v1 = *(const float4*)(p + 4);
        u16x8 o;
        o[0] = f2bf(v0.x); o[1] = f2bf(v0.y); o[2] = f2bf(v0.z); o[3] = f2bf(v0.w);
        o[4] = f2bf(v1.x); o[5] = f2bf(v1.y); o[6] = f2bf(v1.z); o[7] = f2bf(v1.w);
        *(u16x8*)(xb + i * 8) = o;
        return;
    }
    int idx = blockIdx.x * 256 + threadIdx.x;
    float gA = 1.f / (1.f + expf(-gate1[0]));   // layer processed FIRST uses params *1
    float gB = 1.f / (1.f + expf(-gate0[0]));
    if (idx < 256 * 512) {
        int n = idx >> 9, k = idx & 511;
        float v;
        if (k < 256) v = wl1[n * 256 + k];
        else         v = (1.f - gA) * w01[n * 256 + (k - 256)] + gA * w11[n * 256 + (k - 256)];
        WcatA[idx] = f2bf(v);
    } else if (idx < 256 * 512 + 256 * 768) {
        int j = idx - 256 * 512;
        int n = j / 768, k = j - n * 768;
        float v;
        if (k < 256)      v = wl0[n * 256 + k];
        else if (k < 512) v = (1.f - gB) * w00[n * 256 + (k - 256)];
        else              v = gB * w10[n * 256 + (k - 512)];
        WcatB[j] = f2bf(v);
    } else {
        int j = idx - (256 * 512 + 256 * 768);
        if (j < OUTC * C) Woutb[j] = f2bf(Wout[j]);
    }
    if (idx < 512) {
        int nn = idx & 255;
        if (idx < 256) bcat[idx] = bl1[nn] + (1.f - gA) * b01[nn] + gA * b11[nn];
        else           bcat[idx] = bl0[nn] + (1.f - gB) * b00[nn] + gB * b10[nn];
    }
}

// ================= CSR build (both graphs per launch) =============================
__global__ void count_edges2(const int* __restrict__ ei1, const int* __restrict__ ei0,
                             int* __restrict__ cnt1, int* __restrict__ deg1,
                             int* __restrict__ cnt0, int* __restrict__ deg0,
                             int E, int Nn, int ebg)
{
    int b = blockIdx.x;
    const int* ei; int *cnt, *deg;
    if (b < ebg) { ei = ei1; cnt = cnt1; deg = deg1; }
    else         { b -= ebg; ei = ei0; cnt = cnt0; deg = deg0; }
    int idx = b * 256 + threadIdx.x;
    if (idx >= E) return;
    int s = ei[idx], d = ei[E + idx];
    if ((unsigned)s >= (unsigned)Nn || (unsigned)d >= (unsigned)Nn) return;
    atomicAdd(cnt + s, 1);
    atomicAdd(deg + d, 1);
}

__global__ void block_sums2(const int* __restrict__ cnt1, const int* __restrict__ cnt0,
                            int* __restrict__ parts1, int* __restrict__ parts0,
                            int n, int nblk)
{
    int b = blockIdx.x;
    const int* counts; int* partials;
    if (b < nblk) { counts = cnt1; partials = parts1; }
    else          { b -= nblk; counts = cnt0; partials = parts0; }
    int i = b * 256 + threadIdx.x;
    int v = (i < n) ? counts[i] : 0;
    #pragma unroll
    for (int off = 32; off; off >>= 1) v += __shfl_down(v, off, 64);
    __shared__ int ws[4];
    if ((threadIdx.x & 63) == 0) ws[threadIdx.x >> 6] = v;
    __syncthreads();
    if (threadIdx.x == 0) partials[b] = ws[0] + ws[1] + ws[2] + ws[3];
}

__global__ void scan_partials2(int* __restrict__ parts1, int* __restrict__ parts0, int nblk)
{
    int* partials = blockIdx.x ? parts0 : parts1;
    __shared__ int buf[1024];
    int tid = threadIdx.x;
    int v = (tid < nblk) ? partials[tid] : 0;
    buf[tid] = v; __syncthreads();
    for (int off = 1; off < 1024; off <<= 1) {
        int t = (tid >= off) ? buf[tid - off] : 0;
        __syncthreads();
        buf[tid] += t;
        __syncthreads();
    }
    if (tid < nblk) partials[tid] = buf[tid] - v;
}

__global__ void make_offsets2(int* __restrict__ cnt1, int* __restrict__ cnt0,
                              const int* __restrict__ parts1, const int* __restrict__ parts0,
                              int* __restrict__ off1a, int* __restrict__ off0a,
                              int n, int nblk)
{
    int b = blockIdx.x;
    int* counts_cursor; const int* partials; int* offsets;
    if (b < nblk) { counts_cursor = cnt1; partials = parts1; offsets = off1a; }
    else          { b -= nblk; counts_cursor = cnt0; partials = parts0; offsets = off0a; }
    __shared__ int buf[256];
    int i = b * 256 + threadIdx.x;
    int cnt = (i < n) ? counts_cursor[i] : 0;
    buf[threadIdx.x] = cnt; __syncthreads();
    for (int off = 1; off < 256; off <<= 1) {
        int t = (threadIdx.x >= off) ? buf[threadIdx.x - off] : 0;
        __syncthreads();
        buf[threadIdx.x] += t;
        __syncthreads();
    }
    int off = partials[b] + buf[threadIdx.x] - cnt;
    if (i < n) {
        offsets[i] = off;
        counts_cursor[i] = off;
        if (i == n - 1) offsets[n] = off + cnt;
    }
}

__global__ void fill_edges2(const int* __restrict__ ei1, const int* __restrict__ ei0,
                            int* __restrict__ cur1, int* __restrict__ cur0,
                            int* __restrict__ ed1, int* __restrict__ ed0,
                            int E, int Nn, int ebg)
{
    int b = blockIdx.x;
    const int* ei; int *cursor, *edgedst;
    if (b < ebg) { ei = ei1; cursor = cur1; edgedst = ed1; }
    else         { b -= ebg; ei = ei0; cursor = cur0; edgedst = ed0; }
    int idx = b * 256 + threadIdx.x;
    if (idx >= E) return;
    int s = ei[idx], d = ei[E + idx];
    if ((unsigned)s >= (unsigned)Nn || (unsigned)d >= (unsigned)Nn) return;
    int p = atomicAdd(cursor + s, 1);
    edgedst[p] = d;
}

// ---- gather: one wave per node; lanes 0-31 / 32-63 cover 2 edges, 16B per lane ---
__global__ __launch_bounds__(256) void gather_kernel(
    const int* __restrict__ offsets, const int* __restrict__ edgedst,
    const int* __restrict__ degcnt, const u16* __restrict__ h,
    u16* __restrict__ aggb, int Nn)
{
    int node = blockIdx.x * 4 + (threadIdx.x >> 6);
    if (node >= Nn) return;
    int lane = threadIdx.x & 63;
    int half = lane >> 5, l5 = lane & 31;
    int beg = offsets[node], end = offsets[node + 1];
    float a0[8] = {}, a1[8] = {};
    int p = beg;
    for (; p + 3 < end; p += 4) {              // 4 edges in flight
        int d0 = edgedst[p + half];
        int d1 = edgedst[p + 2 + half];
        u16x8 v0 = *(const u16x8*)(h + (size_t)d0 * C + l5 * 8);
        u16x8 v1 = *(const u16x8*)(h + (size_t)d1 * C + l5 * 8);
        #pragma unroll
        for (int j = 0; j < 8; ++j) { a0[j] += bf2f(v0[j]); a1[j] += bf2f(v1[j]); }
    }
    if (p + 1 < end) {                         // remaining pair
        int d0 = edgedst[p + half];
        u16x8 v0 = *(const u16x8*)(h + (size_t)d0 * C + l5 * 8);
        #pragma unroll
        for (int j = 0; j < 8; ++j) a0[j] += bf2f(v0[j]);
        p += 2;
    }
    if (p < end && half == 0) {                // odd tail: lanes 0-31 only
        int d0 = edgedst[p];
        u16x8 v0 = *(const u16x8*)(h + (size_t)d0 * C + l5 * 8);
        #pragma unroll
        for (int j = 0; j < 8; ++j) a1[j] += bf2f(v0[j]);
    }
    float inv = 1.0f / fmaxf((float)degcnt[node], 1.0f);
    u16x8 o;
    #pragma unroll
    for (int j = 0; j < 8; ++j) {
        float s = a0[j] + a1[j];
        s += __shfl_xor(s, 32);                // combine edge-halves
        o[j] = f2bf(s * inv);
    }
    if (half == 0)
        *(u16x8*)(aggb + (size_t)node * C + l5 * 8) = o;
}

// =================================================================================
// layer_gemm8: 256x256 tile GEMM, 2 phases per K-tile (kh0/kh1), counted vmcnt,
// fused bias+ReLU+LN epilogue. If FUSE: LN'd h2 (bf16) goes to the dead A/B LDS
// buffers (XOR-swizzled) and the output projection h2 @ Wout^T + bout is computed
// in-kernel (Wout B-frags read direct from global, L2-hot), fp32 out stored.
// LDS element (r,c16B): phys slot = (((r&1)<<2)|c) ^ ((r>>1)&7)  -> 2-way banks.
// global_load_lds dest is linear; the swizzle is applied on the GLOBAL source.
// =================================================================================
template <int NSEG, bool FUSE>
__global__ __launch_bounds__(512, 2) void layer_gemm8(
    const u16* __restrict__ s0, const u16* __restrict__ s1, const u16* __restrict__ s2,
    const u16* __restrict__ W,          // [256][NSEG*256] bf16
    const float* __restrict__ bcat,
    const float* __restrict__ lns, const float* __restrict__ lnb,
    u16* __restrict__ Hout,
    const u16* __restrict__ WoutB, const float* __restrict__ boutp,
    float* __restrict__ outp, int Nnodes)
{
    constexpr int WK = NSEG * 256;
    constexpr int T  = NSEG * 4;               // K-tiles of 64

    extern __shared__ char smem[];
    u16*   A_e    = (u16*)smem;                // 2 x 16384 elements (64KB)
    u16*   B_e    = (u16*)(smem + 65536);      // 2 x 16384 elements (64KB)
    float* lnpart = (float*)(smem + 131072);   // [256][4][2] (8KB)
    u16*   h2l    = (u16*)smem;                // FUSE: 256x256 bf16 (128KB, post-loop)

    const int tid  = threadIdx.x;
    const int wave = tid >> 6, lane = tid & 63;
    const int wave_m = wave & 1, wave_n = wave >> 1;   // 2 x 4
    const int q = lane >> 4, l15 = lane & 15;
    const int m0 = blockIdx.x * 256;

    // ---- staging address precompute (2 global_load_lds per 16KB half-tile) ----
    size_t a_goff[2], b_goff[2];
    int ldso[2];
    #pragma unroll
    for (int i = 0; i < 2; ++i) {
        int o = i * 8192 + wave * 1024 + lane * 16;    // linear byte off in half
        int g = o >> 7, slot = (o >> 4) & 7;
        int bc = slot ^ (g & 7);
        int r = 2 * g + (bc >> 2), c = bc & 3;         // logical row/chunk at o
        int node = m0 + r; if (node >= Nnodes) node = Nnodes - 1;
        a_goff[i] = (size_t)node * C + c * 8;
        b_goff[i] = (size_t)r * WK + c * 8;
        ldso[i]   = i * 8192 + wave * 1024;            // wave-uniform LDS base
    }

    // ---- fragment read offsets (elements, within one 8192-elem half) ----
    int aoffE[8], boffE[4];
    #pragma unroll
    for (int j = 0; j < 8; ++j) {
        int r = wave_m * 128 + j * 16 + l15;
        aoffE[j] = (r >> 1) * 64 + (((((r & 1) << 2) | q) ^ ((r >> 1) & 7)) << 3);
    }
    #pragma unroll
    for (int f = 0; f < 4; ++f) {
        int r = wave_n * 64 + f * 16 + l15;
        boffE[f] = (r >> 1) * 64 + (((((r & 1) << 2) | q) ^ ((r >> 1) & 7)) << 3);
    }

    f32x4 acc[8][4] = {};

    auto stA = [&](int buf, int kh, int t) {
        const u16* sp = (t < 4) ? s0 : ((NSEG == 2 || t < 8) ? s1 : s2);
        const u16* base = sp + ((t & 3) << 6) + (kh << 5);
        #pragma unroll
        for (int i = 0; i < 2; ++i)
            load_lds16(base + a_goff[i], (char*)A_e + buf * 32768 + kh * 16384 + ldso[i]);
    };
    auto stB = [&](int buf, int kh, int t) {
        const u16* base = W + (t << 6) + (kh << 5);
        #pragma unroll
        for (int i = 0; i < 2; ++i)
            load_lds16(base + b_goff[i], (char*)B_e + buf * 32768 + kh * 16384 + ldso[i]);
    };

#define LDA(DST, BASE, MH) \
    _Pragma("unroll") for (int j = 0; j < 4; ++j) \
        DST[j] = *(const bf16x8*)((BASE) + aoffE[(MH) * 4 + j]);
#define LDB(DST, BASE) \
    _Pragma("unroll") for (int f = 0; f < 4; ++f) \
        DST[f] = *(const bf16x8*)((BASE) + boffE[f]);
#define MFMA16(MH, AF, BF) \
    _Pragma("unroll") for (int j = 0; j < 4; ++j) \
        _Pragma("unroll") for (int f = 0; f < 4; ++f) \
            acc[(MH) * 4 + j][f] = __builtin_amdgcn_mfma_f32_16x16x32_bf16( \
                AF[j], BF[f], acc[(MH) * 4 + j][f], 0, 0, 0);
#define SBAR()  asm volatile("s_barrier" ::: "memory")

    // prologue: all 4 half-tiles of K-tile 0 (8 loads/wave in flight)
    stA(0, 0, 0); stB(0, 0, 0); stA(0, 1, 0); stB(0, 1, 0);

    int cur = 0;
    for (int t = 0; t < T - 1; ++t, cur ^= 1) {
        const u16* Ac = A_e + cur * 16384;
        const u16* Bc = B_e + cur * 16384;
        const int nxt = cur ^ 1;
        bf16x8 af[4], bfr[4];
        // ---- kh = 0 : stage kh0(t+1), wait kh0(t), 32 MFMA ----
        stA(nxt, 0, t + 1); stB(nxt, 0, t + 1);            // 12 in flight
        asm volatile("s_waitcnt vmcnt(8)" ::: "memory");   // drain kh0 A+B of t
        SBAR();
        __builtin_amdgcn_sched_barrier(0);
        LDB(bfr, Bc); LDA(af, Ac, 0);
        __builtin_amdgcn_s_setprio(1);
        MFMA16(0, af, bfr);
        __builtin_amdgcn_s_setprio(0);
        LDA(af, Ac, 1);
        __builtin_amdgcn_s_setprio(1);
        MFMA16(1, af, bfr);
        __builtin_amdgcn_s_setprio(0);
        SBAR();
        // ---- kh = 1 ----
        stA(nxt, 1, t + 1); stB(nxt, 1, t + 1);            // 12 in flight
        asm volatile("s_waitcnt vmcnt(8)" ::: "memory");   // drain kh1 A+B of t
        SBAR();
        __builtin_amdgcn_sched_barrier(0);
        LDB(bfr, Bc + 8192); LDA(af, Ac + 8192, 0);
        __builtin_amdgcn_s_setprio(1);
        MFMA16(0, af, bfr);
        __builtin_amdgcn_s_setprio(0);
        LDA(af, Ac + 8192, 1);
        __builtin_amdgcn_s_setprio(1);
        MFMA16(1, af, bfr);
        __builtin_amdgcn_s_setprio(0);
        SBAR();
    }
    {   // ---- tail K-tile (no staging; drain 4 then 0) ----
        const u16* Ac = A_e + cur * 16384;
        const u16* Bc = B_e + cur * 16384;
        bf16x8 af[4], bfr[4];
        asm volatile("s_waitcnt vmcnt(4)" ::: "memory");
        SBAR();
        __builtin_amdgcn_sched_barrier(0);
        LDB(bfr, Bc); LDA(af, Ac, 0);
        __builtin_amdgcn_s_setprio(1);
        MFMA16(0, af, bfr);
        __builtin_amdgcn_s_setprio(0);
        LDA(af, Ac, 1);
        __builtin_amdgcn_s_setprio(1);
        MFMA16(1, af, bfr);
        __builtin_amdgcn_s_setprio(0);
        SBAR();
        asm volatile("s_waitcnt vmcnt(0)" ::: "memory");
        SBAR();
        __builtin_amdgcn_sched_barrier(0);
        LDB(bfr, Bc + 8192); LDA(af, Ac + 8192, 0);
        __builtin_amdgcn_s_setprio(1);
        MFMA16(0, af, bfr);
        __builtin_amdgcn_s_setprio(0);
        LDA(af, Ac + 8192, 1);
        __builtin_amdgcn_s_setprio(1);
        MFMA16(1, af, bfr);
        __builtin_amdgcn_s_setprio(0);
    }

    // ---- fused epilogue: bias + relu + LN ----
    float bias[4], lsc[4], lbi[4];
    #pragma unroll
    for (int f = 0; f < 4; ++f) {
        int n = wave_n * 64 + f * 16 + l15;
        bias[f] = bcat[n]; lsc[f] = lns[n]; lbi[f] = lnb[n];
    }
    #pragma unroll
    for (int t8 = 0; t8 < 8; ++t8)
        #pragma unroll
        for (int r = 0; r < 4; ++r) {
            float p = 0.f, pp = 0.f;
            #pragma unroll
            for (int f = 0; f < 4; ++f) {
                float v = acc[t8][f][r] + bias[f];
                v = fmaxf(v, 0.f);
                acc[t8][f][r] = v;
                p += v; pp += v * v;
            }
            #pragma unroll
            for (int off = 1; off < 16; off <<= 1) {
                p  += __shfl_xor(p,  off, 16);
                pp += __shfl_xor(pp, off, 16);
            }
            if (l15 == 0) {
                int row = wave_m * 128 + t8 * 16 + q * 4 + r;
                lnpart[row * 8 + wave_n * 2 + 0] = p;
                lnpart[row * 8 + wave_n * 2 + 1] = pp;
            }
        }
    __syncthreads();      // also: all waves done with A/B LDS -> h2l may overwrite
    #pragma unroll
    for (int t8 = 0; t8 < 8; ++t8)
        #pragma unroll
        for (int r = 0; r < 4; ++r) {
            int row = wave_m * 128 + t8 * 16 + q * 4 + r;
            int node = m0 + row;
            float S1 = lnpart[row * 8 + 0] + lnpart[row * 8 + 2]
                     + lnpart[row * 8 + 4] + lnpart[row * 8 + 6];
            float S2 = lnpart[row * 8 + 1] + lnpart[row * 8 + 3]
                     + lnpart[row * 8 + 5] + lnpart[row * 8 + 7];
            float mean = S1 * (1.f / 256.f);
            float var  = fmaxf(S2 * (1.f / 256.f) - mean * mean, 0.f);
            float rstd = rsqrtf(var + LN_EPS);
            if constexpr (FUSE) {
                #pragma unroll
                for (int f = 0; f < 4; ++f) {
                    int n = wave_n * 64 + f * 16 + l15;
                    u16 hv = f2bf((acc[t8][f][r] - mean) * rstd * lsc[f] + lbi[f]);
                    h2l[row * 256 + (((n >> 3) ^ (row & 7)) << 3) + (n & 7)] = hv;
                }
            } else if (node < Nnodes) {
                u16* op = Hout + (size_t)node * C;
                #pragma unroll
                for (int f = 0; f < 4; ++f) {
                    int n = wave_n * 64 + f * 16 + l15;
                    op[n] = f2bf((acc[t8][f][r] - mean) * rstd * lsc[f] + lbi[f]);
                }
            }
        }

    if constexpr (FUSE) {
        __syncthreads();   // h2l complete
        // ---- out-GEMM: out[256 x 128] = h2l @ WoutB^T + bout ----
        f32x4 acc2[8][2] = {};
        for (int kt = 0; kt < 8; ++kt) {
            bf16x8 bw[2];
            #pragma unroll
            for (int f = 0; f < 2; ++f) {
                int n = wave_n * 32 + f * 16 + l15;
                bw[f] = *(const bf16x8*)(WoutB + (size_t)n * 256 + kt * 32 + q * 8);
            }
            #pragma unroll
            for (int t8 = 0; t8 < 8; ++t8) {
                int row = wave_m * 128 + t8 * 16 + l15;
                bf16x8 a = *(const bf16x8*)(h2l + row * 256
                                            + ((((kt << 2) | q) ^ (row & 7)) << 3));
                #pragma unroll
                for (int f = 0; f < 2; ++f)
                    acc2[t8][f] = __builtin_amdgcn_mfma_f32_16x16x32_bf16(
                        a, bw[f], acc2[t8][f], 0, 0, 0);
            }
        }
        float b2[2];
        #pragma unroll
        for (int f = 0; f < 2; ++f) b2[f] = boutp[wave_n * 32 + f * 16 + l15];
        #pragma unroll
        for (int t8 = 0; t8 < 8; ++t8)
            #pragma unroll
            for (int r = 0; r < 4; ++r) {
                int row = wave_m * 128 + t8 * 16 + q * 4 + r;
                int node = m0 + row;
                if (node < Nnodes) {
                    float* op = outp + (size_t)node * OUTC;
                    #pragma unroll
                    for (int f = 0; f < 2; ++f)
                        op[wave_n * 32 + f * 16 + l15] = acc2[t8][f][r] + b2[f];
                }
            }
    }
#undef LDA
#undef LDB
#undef MFMA16
#undef SBAR
}

extern "C" void kernel_launch(void* const* d_in, const int* in_sizes, int n_in,
                              void* d_out, int out_size, void* d_ws, size_t ws_size,
                              hipStream_t stream)
{
    const float* x    = (const float*)d_in[0];
    const int*   ei0  = (const int*)d_in[1];
    const int*   ei1  = (const int*)d_in[2];
    const float* wl0  = (const float*)d_in[3];
    const float* bl0  = (const float*)d_in[4];
    const float* w00  = (const float*)d_in[5];
    const float* b00  = (const float*)d_in[6];
    const float* w10  = (const float*)d_in[7];
    const float* b10  = (const float*)d_in[8];
    const float* gate0= (const float*)d_in[9];
    const float* lns0 = (const float*)d_in[10];
    const float* lnb0 = (const float*)d_in[11];
    const float* wl1  = (const float*)d_in[12];
    const float* bl1  = (const float*)d_in[13];
    const float* w01  = (const float*)d_in[14];
    const float* b01  = (const float*)d_in[15];
    const float* w11  = (const float*)d_in[16];
    const float* b11  = (const float*)d_in[17];
    const float* gate1= (const float*)d_in[18];
    const float* lns1 = (const float*)d_in[19];
    const float* lnb1 = (const float*)d_in[20];
    const float* Wout = (const float*)d_in[21];
    const float* bout = (const float*)d_in[22];

    const int N = in_sizes[0] / C;     // 100000
    const int E = in_sizes[1] / 2;     // 400000

    // workspace (~161 MiB)
    char* w = (char*)d_ws;
    u16*   WcatA = (u16*)w;   w += (size_t)256 * 512 * 2;
    u16*   WcatB = (u16*)w;   w += (size_t)256 * 768 * 2;
    u16*   Woutb = (u16*)w;   w += (size_t)OUTC * C * 2;
    float* bcat  = (float*)w; w += 4096;
    int*   cnt1  = (int*)w;   w += (size_t)N * 4;       // 4 contiguous, one memset
    int*   deg1  = (int*)w;   w += (size_t)N * 4;
    int*   cnt0  = (int*)w;   w += (size_t)N * 4;
    int*   deg0  = (int*)w;   w += (size_t)N * 4;
    int*   off1  = (int*)w;   w += (((size_t)(N + 1) * 4) + 255) & ~255ull;
    int*   off0  = (int*)w;   w += (((size_t)(N + 1) * 4) + 255) & ~255ull;
    int*   parts1= (int*)w;   w += 4096;
    int*   parts0= (int*)w;   w += 4096;
    int*   ed1   = (int*)w;   w += (size_t)E * 4;
    int*   ed0   = (int*)w;   w += (size_t)E * 4;
    u16*   xb    = (u16*)w;   w += (size_t)N * C * 2;   // 51.2 MB bf16 copy of x
    u16*   aggb  = (u16*)w;   w += (size_t)N * C * 2;   // 51.2 MB (reused both layers)
    u16*   h1    = (u16*)w;   w += (size_t)N * C * 2;   // 51.2 MB

    const int eb_grid = (E + 255) / 256;
    const int nblk    = (N + 255) / 256;                // 391 <= 1024
    const int gt_grid = (N + 3) / 4;
    const int gm8     = (N + 255) / 256;                // 391 blocks, 256-row tiles
    const size_t n8   = (size_t)N * C / 8;
    const int xc_blk  = (int)((n8 + 255) / 256);
    const size_t lds8 = 139264;                         // 128KB tiles + 8KB lnpart

    hipMemsetAsync(cnt1, 0, (size_t)4 * N * 4, stream);
    prep_combo<<<PREP_BLK + xc_blk, 256, 0, stream>>>(
        wl0, w00, w10, bl0, b00, b10, gate0,
        wl1, w01, w11, bl1, b01, b11, gate1,
        Wout, x, WcatA, WcatB, Woutb, bcat, xb, n8);

    // ---- CSR builds, both graphs per launch ----
    count_edges2 <<<2 * eb_grid, 256, 0, stream>>>(ei1, ei0, cnt1, deg1, cnt0, deg0, E, N, eb_grid);
    block_sums2  <<<2 * nblk, 256, 0, stream>>>(cnt1, cnt0, parts1, parts0, N, nblk);
    scan_partials2<<<2, 1024, 0, stream>>>(parts1, parts0, nblk);
    make_offsets2<<<2 * nblk, 256, 0, stream>>>(cnt1, cnt0, parts1, parts0, off1, off0, N, nblk);
    fill_edges2  <<<2 * eb_grid, 256, 0, stream>>>(ei1, ei0, cnt1, cnt0, ed1, ed0, E, N, eb_grid);

    // ---- layer A: graph ei1, params *1, h = x0 = xb; K = 512 (w0,w1 folded) ----
    gather_kernel<<<gt_grid, 256, 0, stream>>>(off1, ed1, deg1, xb, aggb, N);
    layer_gemm8<2, false><<<gm8, 512, lds8, stream>>>(aggb, xb, nullptr, WcatA, bcat,
                                                      lns1, lnb1, h1,
                                                      nullptr, nullptr, nullptr, N);

    // ---- layer B + fused output projection: graph ei0, params *0 ----
    gather_kernel<<<gt_grid, 256, 0, stream>>>(off0, ed0, deg0, h1, aggb, N);
    layer_gemm8<3, true><<<gm8, 512, lds8, stream>>>(aggb, h1, xb, WcatB, bcat + C,
                                                     lns0, lnb0, nullptr,
                                                     Woutb, bout, (float*)d_out, N);
}